// Round 1
// baseline (1910.511 us; speedup 1.0000x reference)
//
#include <hip/hip_runtime.h>
#include <math.h>

#define B_ 2
#define T_ 1024
#define D_ 1024
#define H_ 16
#define DH_ 64

// ================= generic GEMM: C[M,N] = A[M,K] * B[N,K]^T + bias[N] ===============
// 128x128 tile, KT=16, 256 threads, 8x8 per thread, global->reg prefetch.
__global__ __launch_bounds__(256) void gemm_tn(
    const float* __restrict__ A, const float* __restrict__ Bm,
    const float* __restrict__ bias, float* __restrict__ C,
    int M, int N, int K)
{
  __shared__ float As[16][128];
  __shared__ float Bs[16][128];
  const int tid = threadIdx.x;
  const int m0 = blockIdx.y * 128;
  const int n0 = blockIdx.x * 128;
  const int tx = tid & 15;
  const int ty = tid >> 4;
  const int lr = tid >> 2;          // 0..63
  const int lc = (tid & 3) * 4;     // 0,4,8,12

  const float* Ap  = A  + (size_t)(m0 + lr) * K + lc;
  const float* Ap2 = A  + (size_t)(m0 + lr + 64) * K + lc;
  const float* Bp  = Bm + (size_t)(n0 + lr) * K + lc;
  const float* Bp2 = Bm + (size_t)(n0 + lr + 64) * K + lc;

  float acc[8][8];
#pragma unroll
  for (int i = 0; i < 8; ++i)
#pragma unroll
    for (int j = 0; j < 8; ++j) acc[i][j] = 0.f;

  float4 a0 = *(const float4*)Ap;
  float4 a1 = *(const float4*)Ap2;
  float4 b0 = *(const float4*)Bp;
  float4 b1 = *(const float4*)Bp2;

  for (int k0 = 0; k0 < K; k0 += 16) {
    __syncthreads();
#pragma unroll
    for (int i = 0; i < 4; ++i) {
      As[lc + i][lr]      = ((const float*)&a0)[i];
      As[lc + i][lr + 64] = ((const float*)&a1)[i];
      Bs[lc + i][lr]      = ((const float*)&b0)[i];
      Bs[lc + i][lr + 64] = ((const float*)&b1)[i];
    }
    __syncthreads();
    if (k0 + 16 < K) {   // prefetch next K-slab while computing this one
      a0 = *(const float4*)(Ap  + k0 + 16);
      a1 = *(const float4*)(Ap2 + k0 + 16);
      b0 = *(const float4*)(Bp  + k0 + 16);
      b1 = *(const float4*)(Bp2 + k0 + 16);
    }
#pragma unroll
    for (int kk = 0; kk < 16; ++kk) {
      const float4 av0 = *(const float4*)&As[kk][ty * 8];
      const float4 av1 = *(const float4*)&As[kk][ty * 8 + 4];
      const float4 bv0 = *(const float4*)&Bs[kk][tx * 8];
      const float4 bv1 = *(const float4*)&Bs[kk][tx * 8 + 4];
      const float a_[8] = {av0.x, av0.y, av0.z, av0.w, av1.x, av1.y, av1.z, av1.w};
      const float b_[8] = {bv0.x, bv0.y, bv0.z, bv0.w, bv1.x, bv1.y, bv1.z, bv1.w};
#pragma unroll
      for (int i = 0; i < 8; ++i)
#pragma unroll
        for (int j = 0; j < 8; ++j)
          acc[i][j] = fmaf(a_[i], b_[j], acc[i][j]);
    }
  }

#pragma unroll
  for (int i = 0; i < 8; ++i) {
    const int row = m0 + ty * 8 + i;
#pragma unroll
    for (int j4 = 0; j4 < 8; j4 += 4) {
      const int col = n0 + tx * 8 + j4;
      float4 c;
      c.x = acc[i][j4 + 0] + bias[col + 0];
      c.y = acc[i][j4 + 1] + bias[col + 1];
      c.z = acc[i][j4 + 2] + bias[col + 2];
      c.w = acc[i][j4 + 3] + bias[col + 3];
      *(float4*)(C + (size_t)row * N + col) = c;
    }
  }
}

// ============ line projections + exterior products + J6 permute ============
// Block handles 8 consecutive t for one b. 256 threads: thread j computes
// output column (j%64) of matrix (j/64) in {W1w(x_prev), W2w(x), W1r(x), W2r(x)}
// for all 8 t. Then 128 threads compute the 8*16 (t,h) Plucker lines.
__global__ __launch_bounds__(256) void lines_kernel(
    const float* __restrict__ x,
    const float* __restrict__ W1w, const float* __restrict__ W2w,
    const float* __restrict__ W1r, const float* __restrict__ W2r,
    float* __restrict__ Jw, float* __restrict__ rd)
{
  __shared__ float xs[9][1024];     // rows t0-1 .. t0+7
  __shared__ float lw[8][4][64];    // [t][mat][col]
  const int tid = threadIdx.x;
  const int bid = blockIdx.x;       // 0..255
  const int b = bid >> 7;
  const int t0 = (bid & 127) * 8;

  for (int idx = tid; idx < 9 * 256; idx += 256) {
    const int r = idx >> 8;
    const int c4 = (idx & 255) * 4;
    const int t = t0 - 1 + r;
    float4 v = make_float4(0.f, 0.f, 0.f, 0.f);
    if (t >= 0) v = *(const float4*)(x + ((size_t)b * T_ + t) * D_ + c4);
    *(float4*)&xs[r][c4] = v;
  }
  __syncthreads();

  const int mat = tid >> 6;   // wave-uniform
  const int col = tid & 63;
  const float* Wrow;
  if (mat == 0)      Wrow = W1w + (size_t)col * D_;
  else if (mat == 1) Wrow = W2w + (size_t)col * D_;
  else if (mat == 2) Wrow = W1r + (size_t)col * D_;
  else               Wrow = W2r + (size_t)col * D_;
  const int xoff = (mat == 0) ? 0 : 1;   // w1 uses x_prev

  float acc[8];
#pragma unroll
  for (int i = 0; i < 8; ++i) acc[i] = 0.f;
  for (int d = 0; d < D_; d += 4) {
    const float4 wv = *(const float4*)(Wrow + d);
#pragma unroll
    for (int tt = 0; tt < 8; ++tt) {
      const float4 xv = *(const float4*)&xs[tt + xoff][d];   // LDS broadcast
      acc[tt] += wv.x * xv.x + wv.y * xv.y + wv.z * xv.z + wv.w * xv.w;
    }
  }
#pragma unroll
  for (int tt = 0; tt < 8; ++tt) lw[tt][mat][col] = acc[tt];
  __syncthreads();

  if (tid < 128) {
    const int tt = tid >> 4;
    const int h = tid & 15;
    const int t = t0 + tt;
    const size_t base = ((size_t)(b * H_ + h) * T_ + t) * 6;
    // write lines -> Jw (with J6 permute/sign)
    {
      float p1[4], p2[4];
#pragma unroll
      for (int i = 0; i < 4; ++i) { p1[i] = lw[tt][0][h * 4 + i]; p2[i] = lw[tt][1][h * 4 + i]; }
      const float L0 = p1[0]*p2[1] - p1[1]*p2[0];
      const float L1 = p1[0]*p2[2] - p1[2]*p2[0];
      const float L2 = p1[0]*p2[3] - p1[3]*p2[0];
      const float L3 = p1[1]*p2[2] - p1[2]*p2[1];
      const float L4 = p1[1]*p2[3] - p1[3]*p2[1];
      const float L5 = p1[2]*p2[3] - p1[3]*p2[2];
      const float n = sqrtf(L0*L0 + L1*L1 + L2*L2 + L3*L3 + L4*L4 + L5*L5);
      const float inv = 1.f / fmaxf(n, 1e-12f);
      Jw[base + 0] =  L5 * inv;
      Jw[base + 1] = -L4 * inv;
      Jw[base + 2] =  L3 * inv;
      Jw[base + 3] =  L2 * inv;
      Jw[base + 4] = -L1 * inv;
      Jw[base + 5] =  L0 * inv;
    }
    // read lines -> rd (no permute)
    {
      float p1[4], p2[4];
#pragma unroll
      for (int i = 0; i < 4; ++i) { p1[i] = lw[tt][2][h * 4 + i]; p2[i] = lw[tt][3][h * 4 + i]; }
      const float L0 = p1[0]*p2[1] - p1[1]*p2[0];
      const float L1 = p1[0]*p2[2] - p1[2]*p2[0];
      const float L2 = p1[0]*p2[3] - p1[3]*p2[0];
      const float L3 = p1[1]*p2[2] - p1[2]*p2[1];
      const float L4 = p1[1]*p2[3] - p1[3]*p2[1];
      const float L5 = p1[2]*p2[3] - p1[3]*p2[2];
      const float n = sqrtf(L0*L0 + L1*L1 + L2*L2 + L3*L3 + L4*L4 + L5*L5);
      const float inv = 1.f / fmaxf(n, 1e-12f);
      rd[base + 0] = L0 * inv;
      rd[base + 1] = L1 * inv;
      rd[base + 2] = L2 * inv;
      rd[base + 3] = L3 * inv;
      rd[base + 4] = L4 * inv;
      rd[base + 5] = L5 * inv;
    }
  }
}

// ============ causal 6x6 Gram cumsum + rd_M = rd @ M_causal ============
// One block per (b,h); thread i owns t in [4i,4i+4); chunked prefix over LDS.
__global__ __launch_bounds__(256) void scan_kernel(
    const float* __restrict__ Jw, const float* __restrict__ rd,
    float* __restrict__ rdM)
{
  __shared__ float sc[256][36];
  const int tid = threadIdx.x;
  const int bh = blockIdx.x;
  const float* Jb = Jw  + (size_t)bh * T_ * 6;
  const float* Rb = rd  + (size_t)bh * T_ * 6;
  float*       Ob = rdM + (size_t)bh * T_ * 6;
  const int t0 = tid * 4;

  float M[36];
#pragma unroll
  for (int i = 0; i < 36; ++i) M[i] = 0.f;
  for (int tt = 0; tt < 4; ++tt) {
    float j6[6];
#pragma unroll
    for (int i = 0; i < 6; ++i) j6[i] = Jb[(size_t)(t0 + tt) * 6 + i];
#pragma unroll
    for (int a = 0; a < 6; ++a)
#pragma unroll
      for (int c = 0; c < 6; ++c)
        M[a * 6 + c] = fmaf(j6[a], j6[c], M[a * 6 + c]);
  }
#pragma unroll
  for (int i = 0; i < 36; ++i) sc[tid][i] = M[i];
  __syncthreads();

  float Mp[36];
#pragma unroll
  for (int i = 0; i < 36; ++i) Mp[i] = 0.f;
  for (int j = 0; j < tid; ++j) {   // lockstep, broadcast reads
#pragma unroll
    for (int i = 0; i < 36; ++i) Mp[i] += sc[j][i];
  }

  for (int tt = 0; tt < 4; ++tt) {
    const int t = t0 + tt;
    float j6[6], r6[6];
#pragma unroll
    for (int i = 0; i < 6; ++i) { j6[i] = Jb[(size_t)t * 6 + i]; r6[i] = Rb[(size_t)t * 6 + i]; }
#pragma unroll
    for (int a = 0; a < 6; ++a)
#pragma unroll
      for (int c = 0; c < 6; ++c)
        Mp[a * 6 + c] = fmaf(j6[a], j6[c], Mp[a * 6 + c]);   // now inclusive at t
#pragma unroll
    for (int jj = 0; jj < 6; ++jj) {
      float s = 0.f;
#pragma unroll
      for (int a = 0; a < 6; ++a) s = fmaf(r6[a], Mp[a * 6 + jj], s);
      Ob[(size_t)t * 6 + jj] = s;
    }
  }
}

// ============ fused causal attention with eigen bias (two-pass flash) ============
// One wave per block; lane owns row t = c*64+lane. Pass1: (m,l); Pass2: output.
__global__ __launch_bounds__(64) void attn_kernel(
    const float* __restrict__ qkv, const float* __restrict__ Jw,
    const float* __restrict__ rdM, const float* __restrict__ bias_scale,
    float* __restrict__ attnout)
{
  __shared__ float ks[64][64];
  __shared__ float vs[64][64];
  __shared__ float Jws[64][8];
  const int bid = blockIdx.x;       // B*H*(T/64) = 512
  const int c = bid & 15;
  const int h = (bid >> 4) & 15;
  const int b = bid >> 8;
  const int lane = threadIdx.x;
  const int t = c * 64 + lane;

  float q[64];
  {
    const float* qrow = qkv + ((size_t)(b * T_ + t)) * 3072 + h * 64;
#pragma unroll
    for (int d4 = 0; d4 < 64; d4 += 4) {
      const float4 v = *(const float4*)(qrow + d4);
      q[d4 + 0] = v.x * 0.125f; q[d4 + 1] = v.y * 0.125f;
      q[d4 + 2] = v.z * 0.125f; q[d4 + 3] = v.w * 0.125f;
    }
  }
  const size_t jb = (size_t)(b * H_ + h) * T_;
  float rdm[6];
#pragma unroll
  for (int j = 0; j < 6; ++j) rdm[j] = rdM[(jb + t) * 6 + j];
  const float bsc = bias_scale[h];
  const int nS = c * 64 + 64;

  // ---- pass 1: running max + denominator ----
  float m = -1e30f, l = 0.f;
  for (int s0 = 0; s0 < nS; s0 += 64) {
    __syncthreads();
    for (int idx = lane; idx < 1024; idx += 64) {
      const int r = idx >> 4, c4 = (idx & 15) * 4;
      *(float4*)&ks[r][c4] =
          *(const float4*)(qkv + ((size_t)(b * T_ + s0 + r)) * 3072 + 1024 + h * 64 + c4);
    }
    for (int idx = lane; idx < 384; idx += 64)
      Jws[idx / 6][idx % 6] = Jw[(jb + s0) * 6 + idx];
    __syncthreads();
    const int smax = min(64, t + 1 - s0);
    for (int si = 0; si < smax; ++si) {
      float d0 = 0.f, d1 = 0.f, d2 = 0.f, d3 = 0.f;
#pragma unroll
      for (int d4 = 0; d4 < 64; d4 += 4) {
        const float4 kv = *(const float4*)&ks[si][d4];
        d0 = fmaf(q[d4 + 0], kv.x, d0);
        d1 = fmaf(q[d4 + 1], kv.y, d1);
        d2 = fmaf(q[d4 + 2], kv.z, d2);
        d3 = fmaf(q[d4 + 3], kv.w, d3);
      }
      const float4 j0 = *(const float4*)&Jws[si][0];
      const float4 j1 = *(const float4*)&Jws[si][4];
      const float bb = rdm[0]*j0.x + rdm[1]*j0.y + rdm[2]*j0.z +
                       rdm[3]*j0.w + rdm[4]*j1.x + rdm[5]*j1.y;
      const float logit = (d0 + d1) + (d2 + d3) + fabsf(bb) * bsc;
      const float nm = fmaxf(m, logit);
      l = l * __expf(m - nm) + __expf(logit - nm);
      m = nm;
    }
  }

  // ---- pass 2: output accumulation ----
  const float inv_l = 1.f / l;
  float o[64];
#pragma unroll
  for (int i = 0; i < 64; ++i) o[i] = 0.f;

  for (int s0 = 0; s0 < nS; s0 += 64) {
    __syncthreads();
    for (int idx = lane; idx < 1024; idx += 64) {
      const int r = idx >> 4, c4 = (idx & 15) * 4;
      const size_t rowb = ((size_t)(b * T_ + s0 + r)) * 3072 + h * 64 + c4;
      *(float4*)&ks[r][c4] = *(const float4*)(qkv + rowb + 1024);
      *(float4*)&vs[r][c4] = *(const float4*)(qkv + rowb + 2048);
    }
    for (int idx = lane; idx < 384; idx += 64)
      Jws[idx / 6][idx % 6] = Jw[(jb + s0) * 6 + idx];
    __syncthreads();
    const int smax = min(64, t + 1 - s0);
    for (int si = 0; si < smax; ++si) {
      float d0 = 0.f, d1 = 0.f, d2 = 0.f, d3 = 0.f;
#pragma unroll
      for (int d4 = 0; d4 < 64; d4 += 4) {
        const float4 kv = *(const float4*)&ks[si][d4];
        d0 = fmaf(q[d4 + 0], kv.x, d0);
        d1 = fmaf(q[d4 + 1], kv.y, d1);
        d2 = fmaf(q[d4 + 2], kv.z, d2);
        d3 = fmaf(q[d4 + 3], kv.w, d3);
      }
      const float4 j0 = *(const float4*)&Jws[si][0];
      const float4 j1 = *(const float4*)&Jws[si][4];
      const float bb = rdm[0]*j0.x + rdm[1]*j0.y + rdm[2]*j0.z +
                       rdm[3]*j0.w + rdm[4]*j1.x + rdm[5]*j1.y;
      const float logit = (d0 + d1) + (d2 + d3) + fabsf(bb) * bsc;
      const float p = __expf(logit - m) * inv_l;
#pragma unroll
      for (int d4 = 0; d4 < 64; d4 += 4) {
        const float4 vv = *(const float4*)&vs[si][d4];
        o[d4 + 0] = fmaf(p, vv.x, o[d4 + 0]);
        o[d4 + 1] = fmaf(p, vv.y, o[d4 + 1]);
        o[d4 + 2] = fmaf(p, vv.z, o[d4 + 2]);
        o[d4 + 3] = fmaf(p, vv.w, o[d4 + 3]);
      }
    }
  }

  float* orow = attnout + ((size_t)(b * T_ + t)) * 1024 + h * 64;
#pragma unroll
  for (int d4 = 0; d4 < 64; d4 += 4)
    *(float4*)(orow + d4) = make_float4(o[d4], o[d4 + 1], o[d4 + 2], o[d4 + 3]);
}

// =============================== launcher ===============================
extern "C" void kernel_launch(void* const* d_in, const int* in_sizes, int n_in,
                              void* d_out, int out_size, void* d_ws, size_t ws_size,
                              hipStream_t stream)
{
  (void)in_sizes; (void)n_in; (void)out_size; (void)ws_size;
  const float* x    = (const float*)d_in[0];
  const float* Wqkv = (const float*)d_in[1];
  const float* bqkv = (const float*)d_in[2];
  const float* W1w  = (const float*)d_in[3];
  const float* W2w  = (const float*)d_in[4];
  const float* W1r  = (const float*)d_in[5];
  const float* W2r  = (const float*)d_in[6];
  const float* bsc  = (const float*)d_in[7];
  const float* Wout = (const float*)d_in[8];
  const float* bout = (const float*)d_in[9];
  float* out = (float*)d_out;

  float* ws      = (float*)d_ws;
  float* qkv     = ws;                                  // B*T*3D      = 6291456 f
  float* Jw      = qkv + (size_t)B_ * T_ * 3 * D_;      // B*H*T*6     =  196608 f
  float* rd      = Jw  + (size_t)B_ * H_ * T_ * 6;      //                196608 f
  float* rdM     = rd  + (size_t)B_ * H_ * T_ * 6;      //                196608 f
  float* attnout = rdM + (size_t)B_ * H_ * T_ * 6;      // B*T*D       = 2097152 f

  gemm_tn<<<dim3(3 * D_ / 128, B_ * T_ / 128), 256, 0, stream>>>(
      x, Wqkv, bqkv, qkv, B_ * T_, 3 * D_, D_);
  lines_kernel<<<dim3(B_ * T_ / 8), 256, 0, stream>>>(
      x, W1w, W2w, W1r, W2r, Jw, rd);
  scan_kernel<<<dim3(B_ * H_), 256, 0, stream>>>(Jw, rd, rdM);
  attn_kernel<<<dim3(B_ * H_ * (T_ / 64)), 64, 0, stream>>>(
      qkv, Jw, rdM, bsc, attnout);
  gemm_tn<<<dim3(D_ / 128, B_ * T_ / 128), 256, 0, stream>>>(
      attnout, Wout, bout, out, B_ * T_, D_, D_);
}

// Round 2
// 691.114 us; speedup vs baseline: 2.7644x; 2.7644x over previous
//
#include <hip/hip_runtime.h>
#include <math.h>

#define B_ 2
#define T_ 1024
#define D_ 1024
#define H_ 16
#define DH_ 64

// ================= generic GEMM: C[M,N] = A[M,K] * B[N,K]^T + bias[N] ===============
// 128x128 tile, KT=16, 256 threads, 8x8 per thread, global->reg prefetch.
__global__ __launch_bounds__(256) void gemm_tn(
    const float* __restrict__ A, const float* __restrict__ Bm,
    const float* __restrict__ bias, float* __restrict__ C,
    int M, int N, int K)
{
  __shared__ float As[16][128];
  __shared__ float Bs[16][128];
  const int tid = threadIdx.x;
  const int m0 = blockIdx.y * 128;
  const int n0 = blockIdx.x * 128;
  const int tx = tid & 15;
  const int ty = tid >> 4;
  const int lr = tid >> 2;          // 0..63
  const int lc = (tid & 3) * 4;     // 0,4,8,12

  const float* Ap  = A  + (size_t)(m0 + lr) * K + lc;
  const float* Ap2 = A  + (size_t)(m0 + lr + 64) * K + lc;
  const float* Bp  = Bm + (size_t)(n0 + lr) * K + lc;
  const float* Bp2 = Bm + (size_t)(n0 + lr + 64) * K + lc;

  float acc[8][8];
#pragma unroll
  for (int i = 0; i < 8; ++i)
#pragma unroll
    for (int j = 0; j < 8; ++j) acc[i][j] = 0.f;

  float4 a0 = *(const float4*)Ap;
  float4 a1 = *(const float4*)Ap2;
  float4 b0 = *(const float4*)Bp;
  float4 b1 = *(const float4*)Bp2;

  for (int k0 = 0; k0 < K; k0 += 16) {
    __syncthreads();
#pragma unroll
    for (int i = 0; i < 4; ++i) {
      As[lc + i][lr]      = ((const float*)&a0)[i];
      As[lc + i][lr + 64] = ((const float*)&a1)[i];
      Bs[lc + i][lr]      = ((const float*)&b0)[i];
      Bs[lc + i][lr + 64] = ((const float*)&b1)[i];
    }
    __syncthreads();
    if (k0 + 16 < K) {   // prefetch next K-slab while computing this one
      a0 = *(const float4*)(Ap  + k0 + 16);
      a1 = *(const float4*)(Ap2 + k0 + 16);
      b0 = *(const float4*)(Bp  + k0 + 16);
      b1 = *(const float4*)(Bp2 + k0 + 16);
    }
#pragma unroll
    for (int kk = 0; kk < 16; ++kk) {
      const float4 av0 = *(const float4*)&As[kk][ty * 8];
      const float4 av1 = *(const float4*)&As[kk][ty * 8 + 4];
      const float4 bv0 = *(const float4*)&Bs[kk][tx * 8];
      const float4 bv1 = *(const float4*)&Bs[kk][tx * 8 + 4];
      const float a_[8] = {av0.x, av0.y, av0.z, av0.w, av1.x, av1.y, av1.z, av1.w};
      const float b_[8] = {bv0.x, bv0.y, bv0.z, bv0.w, bv1.x, bv1.y, bv1.z, bv1.w};
#pragma unroll
      for (int i = 0; i < 8; ++i)
#pragma unroll
        for (int j = 0; j < 8; ++j)
          acc[i][j] = fmaf(a_[i], b_[j], acc[i][j]);
    }
  }

#pragma unroll
  for (int i = 0; i < 8; ++i) {
    const int row = m0 + ty * 8 + i;
#pragma unroll
    for (int j4 = 0; j4 < 8; j4 += 4) {
      const int col = n0 + tx * 8 + j4;
      float4 c;
      c.x = acc[i][j4 + 0] + bias[col + 0];
      c.y = acc[i][j4 + 1] + bias[col + 1];
      c.z = acc[i][j4 + 2] + bias[col + 2];
      c.w = acc[i][j4 + 3] + bias[col + 3];
      *(float4*)(C + (size_t)row * N + col) = c;
    }
  }
}

// ============ line projections + exterior products + J6 permute ============
__global__ __launch_bounds__(256) void lines_kernel(
    const float* __restrict__ x,
    const float* __restrict__ W1w, const float* __restrict__ W2w,
    const float* __restrict__ W1r, const float* __restrict__ W2r,
    float* __restrict__ Jw, float* __restrict__ rd)
{
  __shared__ float xs[9][1024];     // rows t0-1 .. t0+7
  __shared__ float lw[8][4][64];    // [t][mat][col]
  const int tid = threadIdx.x;
  const int bid = blockIdx.x;       // 0..255
  const int b = bid >> 7;
  const int t0 = (bid & 127) * 8;

  for (int idx = tid; idx < 9 * 256; idx += 256) {
    const int r = idx >> 8;
    const int c4 = (idx & 255) * 4;
    const int t = t0 - 1 + r;
    float4 v = make_float4(0.f, 0.f, 0.f, 0.f);
    if (t >= 0) v = *(const float4*)(x + ((size_t)b * T_ + t) * D_ + c4);
    *(float4*)&xs[r][c4] = v;
  }
  __syncthreads();

  const int mat = tid >> 6;   // wave-uniform
  const int col = tid & 63;
  const float* Wrow;
  if (mat == 0)      Wrow = W1w + (size_t)col * D_;
  else if (mat == 1) Wrow = W2w + (size_t)col * D_;
  else if (mat == 2) Wrow = W1r + (size_t)col * D_;
  else               Wrow = W2r + (size_t)col * D_;
  const int xoff = (mat == 0) ? 0 : 1;   // w1 uses x_prev

  float acc[8];
#pragma unroll
  for (int i = 0; i < 8; ++i) acc[i] = 0.f;
  for (int d = 0; d < D_; d += 4) {
    const float4 wv = *(const float4*)(Wrow + d);
#pragma unroll
    for (int tt = 0; tt < 8; ++tt) {
      const float4 xv = *(const float4*)&xs[tt + xoff][d];   // LDS broadcast
      acc[tt] += wv.x * xv.x + wv.y * xv.y + wv.z * xv.z + wv.w * xv.w;
    }
  }
#pragma unroll
  for (int tt = 0; tt < 8; ++tt) lw[tt][mat][col] = acc[tt];
  __syncthreads();

  if (tid < 128) {
    const int tt = tid >> 4;
    const int h = tid & 15;
    const int t = t0 + tt;
    const size_t base = ((size_t)(b * H_ + h) * T_ + t) * 6;
    {
      float p1[4], p2[4];
#pragma unroll
      for (int i = 0; i < 4; ++i) { p1[i] = lw[tt][0][h * 4 + i]; p2[i] = lw[tt][1][h * 4 + i]; }
      const float L0 = p1[0]*p2[1] - p1[1]*p2[0];
      const float L1 = p1[0]*p2[2] - p1[2]*p2[0];
      const float L2 = p1[0]*p2[3] - p1[3]*p2[0];
      const float L3 = p1[1]*p2[2] - p1[2]*p2[1];
      const float L4 = p1[1]*p2[3] - p1[3]*p2[1];
      const float L5 = p1[2]*p2[3] - p1[3]*p2[2];
      const float n = sqrtf(L0*L0 + L1*L1 + L2*L2 + L3*L3 + L4*L4 + L5*L5);
      const float inv = 1.f / fmaxf(n, 1e-12f);
      Jw[base + 0] =  L5 * inv;
      Jw[base + 1] = -L4 * inv;
      Jw[base + 2] =  L3 * inv;
      Jw[base + 3] =  L2 * inv;
      Jw[base + 4] = -L1 * inv;
      Jw[base + 5] =  L0 * inv;
    }
    {
      float p1[4], p2[4];
#pragma unroll
      for (int i = 0; i < 4; ++i) { p1[i] = lw[tt][2][h * 4 + i]; p2[i] = lw[tt][3][h * 4 + i]; }
      const float L0 = p1[0]*p2[1] - p1[1]*p2[0];
      const float L1 = p1[0]*p2[2] - p1[2]*p2[0];
      const float L2 = p1[0]*p2[3] - p1[3]*p2[0];
      const float L3 = p1[1]*p2[2] - p1[2]*p2[1];
      const float L4 = p1[1]*p2[3] - p1[3]*p2[1];
      const float L5 = p1[2]*p2[3] - p1[3]*p2[2];
      const float n = sqrtf(L0*L0 + L1*L1 + L2*L2 + L3*L3 + L4*L4 + L5*L5);
      const float inv = 1.f / fmaxf(n, 1e-12f);
      rd[base + 0] = L0 * inv;
      rd[base + 1] = L1 * inv;
      rd[base + 2] = L2 * inv;
      rd[base + 3] = L3 * inv;
      rd[base + 4] = L4 * inv;
      rd[base + 5] = L5 * inv;
    }
  }
}

// ============ causal 6x6 Gram cumsum + rd_M = rd @ M_causal ============
__global__ __launch_bounds__(256) void scan_kernel(
    const float* __restrict__ Jw, const float* __restrict__ rd,
    float* __restrict__ rdM)
{
  __shared__ float sc[256][36];
  const int tid = threadIdx.x;
  const int bh = blockIdx.x;
  const float* Jb = Jw  + (size_t)bh * T_ * 6;
  const float* Rb = rd  + (size_t)bh * T_ * 6;
  float*       Ob = rdM + (size_t)bh * T_ * 6;
  const int t0 = tid * 4;

  float M[36];
#pragma unroll
  for (int i = 0; i < 36; ++i) M[i] = 0.f;
  for (int tt = 0; tt < 4; ++tt) {
    float j6[6];
#pragma unroll
    for (int i = 0; i < 6; ++i) j6[i] = Jb[(size_t)(t0 + tt) * 6 + i];
#pragma unroll
    for (int a = 0; a < 6; ++a)
#pragma unroll
      for (int c = 0; c < 6; ++c)
        M[a * 6 + c] = fmaf(j6[a], j6[c], M[a * 6 + c]);
  }
#pragma unroll
  for (int i = 0; i < 36; ++i) sc[tid][i] = M[i];
  __syncthreads();

  float Mp[36];
#pragma unroll
  for (int i = 0; i < 36; ++i) Mp[i] = 0.f;
  for (int j = 0; j < tid; ++j) {   // lockstep, broadcast reads
#pragma unroll
    for (int i = 0; i < 36; ++i) Mp[i] += sc[j][i];
  }

  for (int tt = 0; tt < 4; ++tt) {
    const int t = t0 + tt;
    float j6[6], r6[6];
#pragma unroll
    for (int i = 0; i < 6; ++i) { j6[i] = Jb[(size_t)t * 6 + i]; r6[i] = Rb[(size_t)t * 6 + i]; }
#pragma unroll
    for (int a = 0; a < 6; ++a)
#pragma unroll
      for (int c = 0; c < 6; ++c)
        Mp[a * 6 + c] = fmaf(j6[a], j6[c], Mp[a * 6 + c]);   // now inclusive at t
#pragma unroll
    for (int jj = 0; jj < 6; ++jj) {
      float s = 0.f;
#pragma unroll
      for (int a = 0; a < 6; ++a) s = fmaf(r6[a], Mp[a * 6 + jj], s);
      Ob[(size_t)t * 6 + jj] = s;
    }
  }
}

// ============ fused causal attention with eigen bias (single-pass flash) ============
// 256 threads = 4 waves. Quad of lanes (r*4+q) co-owns query row w*16+r:
// each quarter handles 16 of the 64 head dims; dot reduced via shfl_xor(1,2).
// Online softmax with deferred max (rescale only when max grows by >8).
__global__ __launch_bounds__(256) void attn_kernel(
    const float* __restrict__ qkv, const float* __restrict__ Jw,
    const float* __restrict__ rdM, const float* __restrict__ bias_scale,
    float* __restrict__ attnout)
{
  __shared__ float ks[64][64];
  __shared__ float vs[64][64];
  __shared__ float Jws[64][8];
  const int bid = blockIdx.x;       // B*H*(T/64) = 512
  const int c = bid & 15;
  const int h = (bid >> 4) & 15;
  const int b = bid >> 8;
  const int tid = threadIdx.x;
  const int w = tid >> 6;           // wave 0..3
  const int lane = tid & 63;
  const int r = lane >> 2;          // row within wave's 16
  const int qq = lane & 3;          // dim-quarter
  const int row = w * 16 + r;       // row within 64-chunk
  const int t = c * 64 + row;

  // q quarter (pre-scaled by 1/sqrt(dh))
  float q[16];
  {
    const float* qrow = qkv + ((size_t)(b * T_ + t)) * 3072 + h * 64 + qq * 16;
#pragma unroll
    for (int d4 = 0; d4 < 16; d4 += 4) {
      const float4 v = *(const float4*)(qrow + d4);
      q[d4 + 0] = v.x * 0.125f; q[d4 + 1] = v.y * 0.125f;
      q[d4 + 2] = v.z * 0.125f; q[d4 + 3] = v.w * 0.125f;
    }
  }
  const size_t jb = (size_t)(b * H_ + h) * T_;
  float rdm[6];
#pragma unroll
  for (int j = 0; j < 6; ++j) rdm[j] = rdM[(jb + t) * 6 + j];
  const float bsc = bias_scale[h];
  const int nS = c * 64 + 64;

  float m = -1e30f, l = 0.f;
  float o[16];
#pragma unroll
  for (int i = 0; i < 16; ++i) o[i] = 0.f;

  for (int s0 = 0; s0 < nS; s0 += 64) {
    __syncthreads();
    // stage K,V tile (64x64 each) + Jw tile
    for (int idx = tid; idx < 1024; idx += 256) {
      const int sr = idx >> 4, c4 = (idx & 15) * 4;
      const size_t rowb = ((size_t)(b * T_ + s0 + sr)) * 3072 + h * 64 + c4;
      *(float4*)&ks[sr][c4] = *(const float4*)(qkv + rowb + 1024);
      *(float4*)&vs[sr][c4] = *(const float4*)(qkv + rowb + 2048);
    }
    for (int idx = tid; idx < 384; idx += 256)
      Jws[idx / 6][idx % 6] = Jw[(jb + s0) * 6 + idx];
    __syncthreads();

    const int smax = min(64, t + 1 - s0);
    for (int si = 0; si < smax; ++si) {
      // 16-dim partial dot (4 independent accumulators)
      float a0 = 0.f, a1 = 0.f, a2 = 0.f, a3 = 0.f;
      const float4 k0 = *(const float4*)&ks[si][qq * 16 + 0];
      const float4 k1 = *(const float4*)&ks[si][qq * 16 + 4];
      const float4 k2 = *(const float4*)&ks[si][qq * 16 + 8];
      const float4 k3 = *(const float4*)&ks[si][qq * 16 + 12];
      a0 = fmaf(q[0], k0.x, fmaf(q[1], k0.y, fmaf(q[2], k0.z, q[3] * k0.w)));
      a1 = fmaf(q[4], k1.x, fmaf(q[5], k1.y, fmaf(q[6], k1.z, q[7] * k1.w)));
      a2 = fmaf(q[8], k2.x, fmaf(q[9], k2.y, fmaf(q[10], k2.z, q[11] * k2.w)));
      a3 = fmaf(q[12], k3.x, fmaf(q[13], k3.y, fmaf(q[14], k3.z, q[15] * k3.w)));
      float dot = (a0 + a1) + (a2 + a3);
      dot += __shfl_xor(dot, 1);
      dot += __shfl_xor(dot, 2);     // full 64-dim dot in all 4 quad lanes

      const float4 j0 = *(const float4*)&Jws[si][0];
      const float4 j1 = *(const float4*)&Jws[si][4];
      const float bb = rdm[0]*j0.x + rdm[1]*j0.y + rdm[2]*j0.z +
                       rdm[3]*j0.w + rdm[4]*j1.x + rdm[5]*j1.y;
      const float logit = dot + fabsf(bb) * bsc;

      if (__any(logit > m + 8.f)) {   // rare, wave-uniform rescale
        const float nm = fmaxf(m, logit);
        const float sc = __expf(m - nm);
        l *= sc;
#pragma unroll
        for (int i = 0; i < 16; ++i) o[i] *= sc;
        m = nm;
      }
      const float p = __expf(logit - m);
      l += p;
      const float4 v0 = *(const float4*)&vs[si][qq * 16 + 0];
      const float4 v1 = *(const float4*)&vs[si][qq * 16 + 4];
      const float4 v2 = *(const float4*)&vs[si][qq * 16 + 8];
      const float4 v3 = *(const float4*)&vs[si][qq * 16 + 12];
      o[0]  = fmaf(p, v0.x, o[0]);  o[1]  = fmaf(p, v0.y, o[1]);
      o[2]  = fmaf(p, v0.z, o[2]);  o[3]  = fmaf(p, v0.w, o[3]);
      o[4]  = fmaf(p, v1.x, o[4]);  o[5]  = fmaf(p, v1.y, o[5]);
      o[6]  = fmaf(p, v1.z, o[6]);  o[7]  = fmaf(p, v1.w, o[7]);
      o[8]  = fmaf(p, v2.x, o[8]);  o[9]  = fmaf(p, v2.y, o[9]);
      o[10] = fmaf(p, v2.z, o[10]); o[11] = fmaf(p, v2.w, o[11]);
      o[12] = fmaf(p, v3.x, o[12]); o[13] = fmaf(p, v3.y, o[13]);
      o[14] = fmaf(p, v3.z, o[14]); o[15] = fmaf(p, v3.w, o[15]);
    }
  }

  const float inv_l = 1.f / l;
  float* orow = attnout + ((size_t)(b * T_ + t)) * 1024 + h * 64 + qq * 16;
#pragma unroll
  for (int d4 = 0; d4 < 16; d4 += 4) {
    float4 ov;
    ov.x = o[d4 + 0] * inv_l; ov.y = o[d4 + 1] * inv_l;
    ov.z = o[d4 + 2] * inv_l; ov.w = o[d4 + 3] * inv_l;
    *(float4*)(orow + d4) = ov;
  }
}

// =============================== launcher ===============================
extern "C" void kernel_launch(void* const* d_in, const int* in_sizes, int n_in,
                              void* d_out, int out_size, void* d_ws, size_t ws_size,
                              hipStream_t stream)
{
  (void)in_sizes; (void)n_in; (void)out_size; (void)ws_size;
  const float* x    = (const float*)d_in[0];
  const float* Wqkv = (const float*)d_in[1];
  const float* bqkv = (const float*)d_in[2];
  const float* W1w  = (const float*)d_in[3];
  const float* W2w  = (const float*)d_in[4];
  const float* W1r  = (const float*)d_in[5];
  const float* W2r  = (const float*)d_in[6];
  const float* bsc  = (const float*)d_in[7];
  const float* Wout = (const float*)d_in[8];
  const float* bout = (const float*)d_in[9];
  float* out = (float*)d_out;

  float* ws      = (float*)d_ws;
  float* qkv     = ws;                                  // B*T*3D      = 6291456 f
  float* Jw      = qkv + (size_t)B_ * T_ * 3 * D_;      // B*H*T*6     =  196608 f
  float* rd      = Jw  + (size_t)B_ * H_ * T_ * 6;      //                196608 f
  float* rdM     = rd  + (size_t)B_ * H_ * T_ * 6;      //                196608 f
  float* attnout = rdM + (size_t)B_ * H_ * T_ * 6;      // B*T*D       = 2097152 f

  gemm_tn<<<dim3(3 * D_ / 128, B_ * T_ / 128), 256, 0, stream>>>(
      x, Wqkv, bqkv, qkv, B_ * T_, 3 * D_, D_);
  lines_kernel<<<dim3(B_ * T_ / 8), 256, 0, stream>>>(
      x, W1w, W2w, W1r, W2r, Jw, rd);
  scan_kernel<<<dim3(B_ * H_), 256, 0, stream>>>(Jw, rd, rdM);
  attn_kernel<<<dim3(B_ * H_ * (T_ / 64)), 256, 0, stream>>>(
      qkv, Jw, rdM, bsc, attnout);
  gemm_tn<<<dim3(D_ / 128, B_ * T_ / 128), 256, 0, stream>>>(
      attnout, Wout, bout, out, B_ * T_, D_, D_);
}

// Round 4
// 193.550 us; speedup vs baseline: 9.8709x; 3.5707x over previous
//
#include <hip/hip_runtime.h>
#include <math.h>

#define B_ 2
#define T_ 1024
#define D_ 1024
#define H_ 16

typedef __attribute__((ext_vector_type(8))) short bf16x8;
typedef __attribute__((ext_vector_type(4))) float f32x4;

// round-half-up f32->bf16 (cheap, <=0.5ulp)
__device__ inline unsigned short f2bf(float x) {
  return (unsigned short)((__float_as_uint(x) + 0x8000u) >> 16);
}
// pack two f32 -> dword of 2 bf16 (lo, hi)
__device__ inline unsigned bfpack(float lo, float hi) {
  unsigned a = __float_as_uint(hi) + 0x8000u;
  unsigned b = __float_as_uint(lo) + 0x8000u;
  return __builtin_amdgcn_perm(a, b, 0x07060302);
}
__device__ inline void hl_split(float x, unsigned short& h, unsigned short& l) {
  unsigned short hh = f2bf(x);
  float hf = __uint_as_float(((unsigned)hh) << 16);
  l = f2bf(x - hf);
  h = hh;
}

// ============ bf16 MFMA GEMM: C[M,N] = A[M,K] * B[N,K]^T + bias[N] ============
// 128x128 tile, BK=32, 4 waves (2x2), per-wave 64x64 = 4x4 16x16 frags.
__global__ __launch_bounds__(256) void gemm_bf16(
    const float* __restrict__ A, const float* __restrict__ Bm,
    const float* __restrict__ bias, float* __restrict__ C,
    int M, int N, int K)
{
  __shared__ __align__(16) unsigned short As[128][40];  // 32 bf16 + pad
  __shared__ __align__(16) unsigned short Bs[128][40];
  const int tid = threadIdx.x;
  const int m0 = blockIdx.y * 128, n0 = blockIdx.x * 128;
  const int w = tid >> 6, lane = tid & 63;
  const int lr = lane & 15, g = lane >> 4;
  const int wm = (w >> 1) * 64, wn = (w & 1) * 64;
  const int row = tid >> 1, half = tid & 1;

  const float* Ap = A + (size_t)(m0 + row) * K + half * 16;
  const float* Bp = Bm + (size_t)(n0 + row) * K + half * 16;

  f32x4 acc[4][4];
  const f32x4 zf = {0.f, 0.f, 0.f, 0.f};
#pragma unroll
  for (int i = 0; i < 4; ++i)
#pragma unroll
    for (int j = 0; j < 4; ++j) acc[i][j] = zf;

  float4 ar[4], br[4];
#pragma unroll
  for (int i = 0; i < 4; ++i) {
    ar[i] = *(const float4*)(Ap + i * 4);
    br[i] = *(const float4*)(Bp + i * 4);
  }

  for (int k0 = 0; k0 < K; k0 += 32) {
    __syncthreads();
    {
      unsigned a0 = bfpack(ar[0].x, ar[0].y), a1 = bfpack(ar[0].z, ar[0].w);
      unsigned a2 = bfpack(ar[1].x, ar[1].y), a3 = bfpack(ar[1].z, ar[1].w);
      unsigned a4 = bfpack(ar[2].x, ar[2].y), a5 = bfpack(ar[2].z, ar[2].w);
      unsigned a6 = bfpack(ar[3].x, ar[3].y), a7 = bfpack(ar[3].z, ar[3].w);
      *(uint4*)&As[row][half * 16]     = make_uint4(a0, a1, a2, a3);
      *(uint4*)&As[row][half * 16 + 8] = make_uint4(a4, a5, a6, a7);
      unsigned b0 = bfpack(br[0].x, br[0].y), b1 = bfpack(br[0].z, br[0].w);
      unsigned b2 = bfpack(br[1].x, br[1].y), b3 = bfpack(br[1].z, br[1].w);
      unsigned b4 = bfpack(br[2].x, br[2].y), b5 = bfpack(br[2].z, br[2].w);
      unsigned b6 = bfpack(br[3].x, br[3].y), b7 = bfpack(br[3].z, br[3].w);
      *(uint4*)&Bs[row][half * 16]     = make_uint4(b0, b1, b2, b3);
      *(uint4*)&Bs[row][half * 16 + 8] = make_uint4(b4, b5, b6, b7);
    }
    __syncthreads();
    if (k0 + 32 < K) {
#pragma unroll
      for (int i = 0; i < 4; ++i) {
        ar[i] = *(const float4*)(Ap + k0 + 32 + i * 4);
        br[i] = *(const float4*)(Bp + k0 + 32 + i * 4);
      }
    }
    bf16x8 af[4], bfr[4];
#pragma unroll
    for (int i = 0; i < 4; ++i) {
      af[i]  = *(const bf16x8*)&As[wm + i * 16 + lr][g * 8];
      bfr[i] = *(const bf16x8*)&Bs[wn + i * 16 + lr][g * 8];
    }
#pragma unroll
    for (int i = 0; i < 4; ++i)
#pragma unroll
      for (int j = 0; j < 4; ++j)
        acc[i][j] = __builtin_amdgcn_mfma_f32_16x16x32_bf16(af[i], bfr[j], acc[i][j], 0, 0, 0);
  }

#pragma unroll
  for (int i = 0; i < 4; ++i) {
    const int rbase = m0 + wm + i * 16 + 4 * g;
#pragma unroll
    for (int j = 0; j < 4; ++j) {
      const int col = n0 + wn + j * 16 + lr;
      const float bb = bias[col];
#pragma unroll
      for (int r = 0; r < 4; ++r)
        C[(size_t)(rbase + r) * N + col] = acc[i][j][r] + bb;
    }
  }
}

// ============ line projections + exterior products + J6 permute ============
// Jwpk per (bh,t): 16 dwords of bf16 pairs [H01 H23 H45][L01 L23 L45][H01 H23 H45][0 x7]
__global__ __launch_bounds__(256) void lines_kernel(
    const float* __restrict__ x,
    const float* __restrict__ W1w, const float* __restrict__ W2w,
    const float* __restrict__ W1r, const float* __restrict__ W2r,
    float* __restrict__ Jw, float* __restrict__ rd,
    unsigned* __restrict__ Jwpk)
{
  __shared__ float xs[9][1024];
  __shared__ float lw[8][4][64];
  const int tid = threadIdx.x;
  const int bid = blockIdx.x;
  const int b = bid >> 7;
  const int t0 = (bid & 127) * 8;

  for (int idx = tid; idx < 9 * 256; idx += 256) {
    const int r = idx >> 8;
    const int c4 = (idx & 255) * 4;
    const int t = t0 - 1 + r;
    float4 v = make_float4(0.f, 0.f, 0.f, 0.f);
    if (t >= 0) v = *(const float4*)(x + ((size_t)b * T_ + t) * D_ + c4);
    *(float4*)&xs[r][c4] = v;
  }
  __syncthreads();

  const int mat = tid >> 6;
  const int col = tid & 63;
  const float* Wrow;
  if (mat == 0)      Wrow = W1w + (size_t)col * D_;
  else if (mat == 1) Wrow = W2w + (size_t)col * D_;
  else if (mat == 2) Wrow = W1r + (size_t)col * D_;
  else               Wrow = W2r + (size_t)col * D_;
  const int xoff = (mat == 0) ? 0 : 1;

  float acc[8];
#pragma unroll
  for (int i = 0; i < 8; ++i) acc[i] = 0.f;
  for (int d = 0; d < D_; d += 4) {
    const float4 wv = *(const float4*)(Wrow + d);
#pragma unroll
    for (int tt = 0; tt < 8; ++tt) {
      const float4 xv = *(const float4*)&xs[tt + xoff][d];
      acc[tt] += wv.x * xv.x + wv.y * xv.y + wv.z * xv.z + wv.w * xv.w;
    }
  }
#pragma unroll
  for (int tt = 0; tt < 8; ++tt) lw[tt][mat][col] = acc[tt];
  __syncthreads();

  if (tid < 128) {
    const int tt = tid >> 4;
    const int h = tid & 15;
    const int t = t0 + tt;
    const size_t base = ((size_t)(b * H_ + h) * T_ + t) * 6;
    {
      float p1[4], p2[4];
#pragma unroll
      for (int i = 0; i < 4; ++i) { p1[i] = lw[tt][0][h * 4 + i]; p2[i] = lw[tt][1][h * 4 + i]; }
      const float L0 = p1[0]*p2[1] - p1[1]*p2[0];
      const float L1 = p1[0]*p2[2] - p1[2]*p2[0];
      const float L2 = p1[0]*p2[3] - p1[3]*p2[0];
      const float L3 = p1[1]*p2[2] - p1[2]*p2[1];
      const float L4 = p1[1]*p2[3] - p1[3]*p2[1];
      const float L5 = p1[2]*p2[3] - p1[3]*p2[2];
      const float n = sqrtf(L0*L0 + L1*L1 + L2*L2 + L3*L3 + L4*L4 + L5*L5);
      const float inv = 1.f / fmaxf(n, 1e-12f);
      float jv[6] = {L5 * inv, -L4 * inv, L3 * inv, L2 * inv, -L1 * inv, L0 * inv};
#pragma unroll
      for (int i = 0; i < 6; ++i) Jw[base + i] = jv[i];
      unsigned short JH[6], JL[6];
#pragma unroll
      for (int i = 0; i < 6; ++i) hl_split(jv[i], JH[i], JL[i]);
      unsigned* jp = Jwpk + (((size_t)(b * H_ + h) * T_ + t) << 4);
      unsigned h01 = JH[0] | ((unsigned)JH[1] << 16);
      unsigned h23 = JH[2] | ((unsigned)JH[3] << 16);
      unsigned h45 = JH[4] | ((unsigned)JH[5] << 16);
      jp[0] = h01; jp[1] = h23; jp[2] = h45;
      jp[3] = JL[0] | ((unsigned)JL[1] << 16);
      jp[4] = JL[2] | ((unsigned)JL[3] << 16);
      jp[5] = JL[4] | ((unsigned)JL[5] << 16);
      jp[6] = h01; jp[7] = h23; jp[8] = h45;
#pragma unroll
      for (int i = 9; i < 16; ++i) jp[i] = 0;
    }
    {
      float p1[4], p2[4];
#pragma unroll
      for (int i = 0; i < 4; ++i) { p1[i] = lw[tt][2][h * 4 + i]; p2[i] = lw[tt][3][h * 4 + i]; }
      const float L0 = p1[0]*p2[1] - p1[1]*p2[0];
      const float L1 = p1[0]*p2[2] - p1[2]*p2[0];
      const float L2 = p1[0]*p2[3] - p1[3]*p2[0];
      const float L3 = p1[1]*p2[2] - p1[2]*p2[1];
      const float L4 = p1[1]*p2[3] - p1[3]*p2[1];
      const float L5 = p1[2]*p2[3] - p1[3]*p2[2];
      const float n = sqrtf(L0*L0 + L1*L1 + L2*L2 + L3*L3 + L4*L4 + L5*L5);
      const float inv = 1.f / fmaxf(n, 1e-12f);
      rd[base + 0] = L0 * inv;
      rd[base + 1] = L1 * inv;
      rd[base + 2] = L2 * inv;
      rd[base + 3] = L3 * inv;
      rd[base + 4] = L4 * inv;
      rd[base + 5] = L5 * inv;
    }
  }
}

// ============ causal 6x6 Gram cumsum + rd_M; emits packed hi/lo rdMpk ============
// rdMpk per (bh,t): 16 dwords [h01 h23 h45][h01 h23 h45][l01 l23 l45][0 x7]
__global__ __launch_bounds__(256) void scan_kernel(
    const float* __restrict__ Jw, const float* __restrict__ rd,
    unsigned* __restrict__ rdMpk)
{
  __shared__ float sc[256][36];
  const int tid = threadIdx.x;
  const int bh = blockIdx.x;
  const float* Jb = Jw + (size_t)bh * T_ * 6;
  const float* Rb = rd + (size_t)bh * T_ * 6;
  const int t0 = tid * 4;

  float M[36];
#pragma unroll
  for (int i = 0; i < 36; ++i) M[i] = 0.f;
  for (int tt = 0; tt < 4; ++tt) {
    float j6[6];
#pragma unroll
    for (int i = 0; i < 6; ++i) j6[i] = Jb[(size_t)(t0 + tt) * 6 + i];
#pragma unroll
    for (int a = 0; a < 6; ++a)
#pragma unroll
      for (int c = 0; c < 6; ++c)
        M[a * 6 + c] = fmaf(j6[a], j6[c], M[a * 6 + c]);
  }
#pragma unroll
  for (int i = 0; i < 36; ++i) sc[tid][i] = M[i];
  __syncthreads();

  float Mp[36];
#pragma unroll
  for (int i = 0; i < 36; ++i) Mp[i] = 0.f;
  for (int j = 0; j < tid; ++j) {
#pragma unroll
    for (int i = 0; i < 36; ++i) Mp[i] += sc[j][i];
  }

  for (int tt = 0; tt < 4; ++tt) {
    const int t = t0 + tt;
    float j6[6], r6[6];
#pragma unroll
    for (int i = 0; i < 6; ++i) { j6[i] = Jb[(size_t)t * 6 + i]; r6[i] = Rb[(size_t)t * 6 + i]; }
#pragma unroll
    for (int a = 0; a < 6; ++a)
#pragma unroll
      for (int c = 0; c < 6; ++c)
        Mp[a * 6 + c] = fmaf(j6[a], j6[c], Mp[a * 6 + c]);
    float s6[6];
#pragma unroll
    for (int jj = 0; jj < 6; ++jj) {
      float s = 0.f;
#pragma unroll
      for (int a = 0; a < 6; ++a) s = fmaf(r6[a], Mp[a * 6 + jj], s);
      s6[jj] = s;
    }
    unsigned short hh[6], ll[6];
#pragma unroll
    for (int i = 0; i < 6; ++i) hl_split(s6[i], hh[i], ll[i]);
    unsigned* ob = rdMpk + (((size_t)bh * T_ + t) << 4);
    unsigned h01 = hh[0] | ((unsigned)hh[1] << 16);
    unsigned h23 = hh[2] | ((unsigned)hh[3] << 16);
    unsigned h45 = hh[4] | ((unsigned)hh[5] << 16);
    ob[0] = h01; ob[1] = h23; ob[2] = h45;
    ob[3] = h01; ob[4] = h23; ob[5] = h45;
    ob[6] = ll[0] | ((unsigned)ll[1] << 16);
    ob[7] = ll[2] | ((unsigned)ll[3] << 16);
    ob[8] = ll[4] | ((unsigned)ll[5] << 16);
#pragma unroll
    for (int i = 9; i < 16; ++i) ob[i] = 0;
  }
}

// ============ MFMA flash attention with eigen bias ============
__global__ __launch_bounds__(256) void attn_mfma(
    const float* __restrict__ qkv,
    const unsigned* __restrict__ Jwpk,
    const unsigned* __restrict__ rdMpk,
    const float* __restrict__ bias_scale,
    float* __restrict__ attnout)
{
  // LDS: KT 64x144B swz bf16 | VT 64x144B transposed | JW 64x16dw | PB 4x16x144B
  __shared__ __align__(16) unsigned char smem[31744];
  unsigned char* KT = smem;
  unsigned char* VT = smem + 9216;
  unsigned*      JW = (unsigned*)(smem + 18432);
  unsigned char* PB = smem + 22528;

  const int gid = blockIdx.x;
  const int bh = gid & 31;
  const int c = (gid < 256) ? (15 - (gid >> 5)) : ((gid - 256) >> 5);  // LPT pairing
  const int b = bh >> 4, h = bh & 15;
  const int tid = threadIdx.x;
  const int w = tid >> 6;
  const int lane = tid & 63;
  const int lr = lane & 15;
  const int g = lane >> 4;
  const int t0 = c * 64;
  const int nT = c + 1;

  const size_t qkvbase = ((size_t)b * T_) * 3072 + h * 64;
  const size_t jb = (size_t)(b * H_ + h) * T_;

  int srow[4], scol[4];
#pragma unroll
  for (int p = 0; p < 4; ++p) {
    const int idx = p * 256 + tid;
    srow[p] = idx >> 4;
    scol[p] = (idx & 15) * 4;
  }

  // ---- stage Q (scaled) into KT, read per-wave A-frags ----
#pragma unroll
  for (int p = 0; p < 4; ++p) {
    const float4 v = *(const float4*)(qkv + qkvbase + (size_t)(t0 + srow[p]) * 3072 + scol[p]);
    const unsigned d0 = bfpack(v.x * 0.125f, v.y * 0.125f);
    const unsigned d1 = bfpack(v.z * 0.125f, v.w * 0.125f);
    const int byte = srow[p] * 144 + ((scol[p] * 2) ^ ((srow[p] & 7) << 4));
    *(uint2*)(KT + byte) = make_uint2(d0, d1);
  }
  __syncthreads();
  bf16x8 qa[2];
  {
    const int qrow = w * 16 + lr;
#pragma unroll
    for (int kb = 0; kb < 2; ++kb) {
      const int byte = qrow * 144 + (((kb * 64) + 16 * g) ^ ((qrow & 7) << 4));
      qa[kb] = *(const bf16x8*)(KT + byte);
    }
  }
  bf16x8 ra;
  {
    const int t = t0 + w * 16 + lr;
    ra = *(const bf16x8*)(rdMpk + ((jb + t) << 4) + g * 4);
  }
  const float bsc = bias_scale[h];
  __syncthreads();

  float m[4], lsum[4];
  f32x4 O[4];
  const f32x4 zf = {0.f, 0.f, 0.f, 0.f};
#pragma unroll
  for (int r = 0; r < 4; ++r) { m[r] = -1e30f; lsum[r] = 0.f; }
#pragma unroll
  for (int d = 0; d < 4; ++d) O[d] = zf;

  // prologue loads
  float4 kreg[4], vreg[4];
  uint4 jreg;
  const int jrow = tid >> 2, jpart = (tid & 3) * 4;
  {
#pragma unroll
    for (int p = 0; p < 4; ++p) {
      const size_t rb = qkvbase + (size_t)srow[p] * 3072 + scol[p];
      kreg[p] = *(const float4*)(qkv + rb + 1024);
      vreg[p] = *(const float4*)(qkv + rb + 2048);
    }
    jreg = *(const uint4*)(Jwpk + ((jb + jrow) << 4) + jpart);
  }

  for (int ti = 0; ti < nT; ++ti) {
    const int s0 = ti * 64;
    __syncthreads();
    // K: row-major swizzled
#pragma unroll
    for (int p = 0; p < 4; ++p) {
      const unsigned d0 = bfpack(kreg[p].x, kreg[p].y);
      const unsigned d1 = bfpack(kreg[p].z, kreg[p].w);
      const int byte = srow[p] * 144 + ((scol[p] * 2) ^ ((srow[p] & 7) << 4));
      *(uint2*)(KT + byte) = make_uint2(d0, d1);
      // V: transposed [d][s]
      const int s = srow[p];
#pragma unroll
      for (int i = 0; i < 4; ++i) {
        const int d = scol[p] + i;
        const float vv = (i == 0) ? vreg[p].x : (i == 1) ? vreg[p].y : (i == 2) ? vreg[p].z : vreg[p].w;
        const int vbyte = d * 144 + ((2 * s) ^ ((d & 7) << 4));
        *(unsigned short*)(VT + vbyte) = f2bf(vv);
      }
    }
    *(uint4*)(JW + jrow * 16 + jpart) = jreg;
    __syncthreads();
    // prefetch next tile
    if (ti + 1 < nT) {
      const int s0n = s0 + 64;
#pragma unroll
      for (int p = 0; p < 4; ++p) {
        const size_t rb = qkvbase + (size_t)(s0n + srow[p]) * 3072 + scol[p];
        kreg[p] = *(const float4*)(qkv + rb + 1024);
        vreg[p] = *(const float4*)(qkv + rb + 2048);
      }
      jreg = *(const uint4*)(Jwpk + ((jb + s0n + jrow) << 4) + jpart);
    }

    // ---- QK^T + bias via MFMA ----
    f32x4 S[4], Sb[4];
#pragma unroll
    for (int cb = 0; cb < 4; ++cb) {
      const int srw = cb * 16 + lr;
      f32x4 a = zf;
#pragma unroll
      for (int kb = 0; kb < 2; ++kb) {
        const int byte = srw * 144 + (((kb * 64) + 16 * g) ^ ((srw & 7) << 4));
        const bf16x8 kf = *(const bf16x8*)(KT + byte);
        a = __builtin_amdgcn_mfma_f32_16x16x32_bf16(qa[kb], kf, a, 0, 0, 0);
      }
      S[cb] = a;
      union { uint4 u; bf16x8 v; } tmp;
      tmp.u = *(const uint4*)(JW + srw * 16 + g * 4);
      Sb[cb] = __builtin_amdgcn_mfma_f32_16x16x32_bf16(ra, tmp.v, zf, 0, 0, 0);
    }

    // ---- online softmax ----
    const bool diag = (s0 == t0);
    float logit[4][4];
#pragma unroll
    for (int cb = 0; cb < 4; ++cb) {
#pragma unroll
      for (int r = 0; r < 4; ++r) {
        float lg = S[cb][r] + fabsf(Sb[cb][r]) * bsc;
        if (diag && (cb * 16 + lr > w * 16 + 4 * g + r)) lg = -1e30f;
        logit[cb][r] = lg;
      }
    }
#pragma unroll
    for (int r = 0; r < 4; ++r) {
      float mx = fmaxf(fmaxf(logit[0][r], logit[1][r]), fmaxf(logit[2][r], logit[3][r]));
      mx = fmaxf(mx, __shfl_xor(mx, 1));
      mx = fmaxf(mx, __shfl_xor(mx, 2));
      mx = fmaxf(mx, __shfl_xor(mx, 4));
      mx = fmaxf(mx, __shfl_xor(mx, 8));
      const float nm = fmaxf(m[r], mx);
      const float sc = __expf(m[r] - nm);
      m[r] = nm;
      lsum[r] *= sc;
#pragma unroll
      for (int d = 0; d < 4; ++d) O[d][r] *= sc;
    }
#pragma unroll
    for (int cb = 0; cb < 4; ++cb) {
#pragma unroll
      for (int r = 0; r < 4; ++r) {
        const float p = __expf(logit[cb][r] - m[r]);
        lsum[r] += p;
        const int q = 4 * g + r;
        const int s = cb * 16 + lr;
        const int byte = w * 2304 + q * 144 + ((2 * s) ^ ((q & 7) << 4));
        *(unsigned short*)(PB + byte) = f2bf(p);
      }
    }
    // same-wave LDS write->read fence
    asm volatile("s_waitcnt lgkmcnt(0)" ::: "memory");
    __builtin_amdgcn_sched_barrier(0);

    // ---- PV via MFMA ----
    bf16x8 pa[2];
#pragma unroll
    for (int kb = 0; kb < 2; ++kb) {
      const int byte = w * 2304 + lr * 144 + (((kb * 64) + 16 * g) ^ ((lr & 7) << 4));
      pa[kb] = *(const bf16x8*)(PB + byte);
    }
#pragma unroll
    for (int db = 0; db < 4; ++db) {
#pragma unroll
      for (int kb = 0; kb < 2; ++kb) {
        const int d = db * 16 + lr;
        const int byte = d * 144 + (((kb * 64) + 16 * g) ^ ((d & 7) << 4));
        const bf16x8 vf = *(const bf16x8*)(VT + byte);
        O[db] = __builtin_amdgcn_mfma_f32_16x16x32_bf16(pa[kb], vf, O[db], 0, 0, 0);
      }
    }
  }

  // ---- finalize ----
#pragma unroll
  for (int r = 0; r < 4; ++r) {
    float l = lsum[r];
    l += __shfl_xor(l, 1);
    l += __shfl_xor(l, 2);
    l += __shfl_xor(l, 4);
    l += __shfl_xor(l, 8);
    lsum[r] = 1.f / l;
  }
  {
    const int qb = w * 16 + 4 * g;
#pragma unroll
    for (int db = 0; db < 4; ++db) {
#pragma unroll
      for (int r = 0; r < 4; ++r) {
        const int t = t0 + qb + r;
        attnout[((size_t)(b * T_ + t)) * 1024 + h * 64 + db * 16 + lr] = O[db][r] * lsum[r];
      }
    }
  }
}

// =============================== launcher ===============================
extern "C" void kernel_launch(void* const* d_in, const int* in_sizes, int n_in,
                              void* d_out, int out_size, void* d_ws, size_t ws_size,
                              hipStream_t stream)
{
  (void)in_sizes; (void)n_in; (void)out_size; (void)ws_size;
  const float* x    = (const float*)d_in[0];
  const float* Wqkv = (const float*)d_in[1];
  const float* bqkv = (const float*)d_in[2];
  const float* W1w  = (const float*)d_in[3];
  const float* W2w  = (const float*)d_in[4];
  const float* W1r  = (const float*)d_in[5];
  const float* W2r  = (const float*)d_in[6];
  const float* bsc  = (const float*)d_in[7];
  const float* Wout = (const float*)d_in[8];
  const float* bout = (const float*)d_in[9];
  float* out = (float*)d_out;

  float*    qkv     = (float*)d_ws;                       // 6291456 f
  float*    Jw      = qkv + (size_t)B_ * T_ * 3 * D_;     //  196608 f
  float*    rd      = Jw + (size_t)B_ * H_ * T_ * 6;      //  196608 f
  unsigned* Jwpk    = (unsigned*)(rd + (size_t)B_ * H_ * T_ * 6);   // 524288 u32
  unsigned* rdMpk   = Jwpk + ((size_t)B_ * H_ * T_ << 4); // 524288 u32
  float*    attnout = (float*)(rdMpk + ((size_t)B_ * H_ * T_ << 4));  // 2097152 f

  gemm_bf16<<<dim3(3 * D_ / 128, B_ * T_ / 128), 256, 0, stream>>>(
      x, Wqkv, bqkv, qkv, B_ * T_, 3 * D_, D_);
  lines_kernel<<<dim3(B_ * T_ / 8), 256, 0, stream>>>(
      x, W1w, W2w, W1r, W2r, Jw, rd, Jwpk);
  scan_kernel<<<dim3(B_ * H_), 256, 0, stream>>>(Jw, rd, rdMpk);
  attn_mfma<<<dim3(B_ * H_ * (T_ / 64)), 256, 0, stream>>>(
      qkv, Jwpk, rdMpk, bsc, attnout);
  gemm_bf16<<<dim3(D_ / 128, B_ * T_ / 128), 256, 0, stream>>>(
      attnout, Wout, bout, out, B_ * T_, D_, D_);
}

// Round 5
// 139.941 us; speedup vs baseline: 13.6523x; 1.3831x over previous
//
#include <hip/hip_runtime.h>
#include <math.h>

#define B_ 2
#define T_ 1024
#define D_ 1024
#define H_ 16
#define NA_ 3328   // augmented qkv width: 3*D + 4*64

typedef __attribute__((ext_vector_type(8))) short bf16x8;
typedef __attribute__((ext_vector_type(4))) float f32x4;

__device__ inline unsigned short f2bf(float x) {
  return (unsigned short)((__float_as_uint(x) + 0x8000u) >> 16);
}
__device__ inline unsigned bfpack(float lo, float hi) {
  unsigned a = __float_as_uint(hi) + 0x8000u;
  unsigned b = __float_as_uint(lo) + 0x8000u;
  return __builtin_amdgcn_perm(a, b, 0x07060302);
}
__device__ inline void hl_split(float x, unsigned short& h, unsigned short& l) {
  unsigned short hh = f2bf(x);
  float hf = __uint_as_float(((unsigned)hh) << 16);
  l = f2bf(x - hf);
  h = hh;
}

// =================== double-buffered bf16 MFMA GEMM core pieces ===================
// LDS tile: [2 bufs][128 rows][32 shorts] per matrix; 16B-slot XOR swizzle (row&3)<<4.
// 256 threads: thread -> (row = tid>>1, half = tid&1) stages 16 f32 -> 8 dwords bf16.
// Waves 2x2; per-wave 64x64 = 4x4 16x16x32 frags.

#define GEMM_PROLOGUE_VARS()                                                   \
  const int tid = threadIdx.x;                                                 \
  const int w = tid >> 6, lane = tid & 63;                                     \
  const int lr = lane & 15, g = lane >> 4;                                     \
  const int wm = (w >> 1) * 64, wn = (w & 1) * 64;                             \
  const int row = tid >> 1, half = tid & 1;                                    \
  const int sw = (row & 3) << 4;                                               \
  const int by0 = (half * 32) ^ sw, by1 = (half * 32 + 16) ^ sw;

#define GEMM_STORE(bufA, bufB, a, b)                                           \
  {                                                                            \
    uint4 lo = make_uint4(bfpack(a[0].x, a[0].y), bfpack(a[0].z, a[0].w),      \
                          bfpack(a[1].x, a[1].y), bfpack(a[1].z, a[1].w));     \
    uint4 hi = make_uint4(bfpack(a[2].x, a[2].y), bfpack(a[2].z, a[2].w),      \
                          bfpack(a[3].x, a[3].y), bfpack(a[3].z, a[3].w));     \
    *(uint4*)(bufA + row * 64 + by0) = lo;                                     \
    *(uint4*)(bufA + row * 64 + by1) = hi;                                     \
    lo = make_uint4(bfpack(b[0].x, b[0].y), bfpack(b[0].z, b[0].w),            \
                    bfpack(b[1].x, b[1].y), bfpack(b[1].z, b[1].w));           \
    hi = make_uint4(bfpack(b[2].x, b[2].y), bfpack(b[2].z, b[2].w),            \
                    bfpack(b[3].x, b[3].y), bfpack(b[3].z, b[3].w));           \
    *(uint4*)(bufB + row * 64 + by0) = lo;                                     \
    *(uint4*)(bufB + row * 64 + by1) = hi;                                     \
  }

#define GEMM_COMPUTE(bufA, bufB)                                               \
  {                                                                            \
    bf16x8 af[4], bfr[4];                                                      \
    _Pragma("unroll") for (int i = 0; i < 4; ++i) {                            \
      const int rr = wm + i * 16 + lr;                                         \
      af[i] = *(const bf16x8*)(bufA + rr * 64 + ((g * 16) ^ ((rr & 3) << 4))); \
    }                                                                          \
    _Pragma("unroll") for (int i = 0; i < 4; ++i) {                            \
      const int rr = wn + i * 16 + lr;                                         \
      bfr[i] = *(const bf16x8*)(bufB + rr * 64 + ((g * 16) ^ ((rr & 3) << 4)));\
    }                                                                          \
    _Pragma("unroll") for (int i = 0; i < 4; ++i)                              \
    _Pragma("unroll") for (int j = 0; j < 4; ++j)                              \
      acc[i][j] = __builtin_amdgcn_mfma_f32_16x16x32_bf16(af[i], bfr[j],       \
                                                          acc[i][j], 0, 0, 0); \
  }

#define GEMM_LOAD(dst, base, slab)                                             \
  _Pragma("unroll") for (int i = 0; i < 4; ++i)                                \
      dst[i] = *(const float4*)(base + (slab) * 32 + i * 4);

// ============ augmented qkv GEMM: [2048, 3328] = x @ [Wqkv;W1w;W2w;W1r;W2r]^T + bias ============
__global__ __launch_bounds__(256) void gemm_qkv(
    const float* __restrict__ A, const float* __restrict__ Wqkv,
    const float* __restrict__ bqkv,
    const float* __restrict__ W1w, const float* __restrict__ W2w,
    const float* __restrict__ W1r, const float* __restrict__ W2r,
    float* __restrict__ C)
{
  __shared__ __align__(16) unsigned char As[2 * 8192];
  __shared__ __align__(16) unsigned char Bs[2 * 8192];
  const int m0 = blockIdx.y * 128, n0 = blockIdx.x * 128;
  GEMM_PROLOGUE_VARS();

  const float* Ap = A + (size_t)(m0 + row) * D_ + half * 16;
  const float* Bp;
  {
    const int cg = n0 + row;
    if (cg < 3072) Bp = Wqkv + (size_t)cg * D_;
    else {
      const int r = cg - 3072;
      const float* Wm = (r < 64) ? W1w : (r < 128) ? W2w : (r < 192) ? W1r : W2r;
      Bp = Wm + (size_t)(r & 63) * D_;
    }
    Bp += half * 16;
  }

  f32x4 acc[4][4];
  const f32x4 zf = {0.f, 0.f, 0.f, 0.f};
#pragma unroll
  for (int i = 0; i < 4; ++i)
#pragma unroll
    for (int j = 0; j < 4; ++j) acc[i][j] = zf;

  float4 aA[4], bA[4], aB[4], bB[4];
  GEMM_LOAD(aA, Ap, 0); GEMM_LOAD(bA, Bp, 0);
  GEMM_STORE(As, Bs, aA, bA);
  GEMM_LOAD(aB, Ap, 1); GEMM_LOAD(bB, Bp, 1);
  __syncthreads();

#pragma unroll 1
  for (int s = 0; s < 32; s += 2) {
    GEMM_COMPUTE(As, Bs);
    GEMM_STORE((As + 8192), (Bs + 8192), aB, bB);
    if (s + 2 < 32) { GEMM_LOAD(aA, Ap, s + 2); GEMM_LOAD(bA, Bp, s + 2); }
    __syncthreads();
    GEMM_COMPUTE((As + 8192), (Bs + 8192));
    if (s + 2 < 32) GEMM_STORE(As, Bs, aA, bA);
    if (s + 3 < 32) { GEMM_LOAD(aB, Ap, s + 3); GEMM_LOAD(bB, Bp, s + 3); }
    __syncthreads();
  }

#pragma unroll
  for (int i = 0; i < 4; ++i) {
    const int rbase = m0 + wm + i * 16 + 4 * g;
#pragma unroll
    for (int j = 0; j < 4; ++j) {
      const int col = n0 + wn + j * 16 + lr;
      const float bb = (col < 3072) ? bqkv[col] : 0.f;
#pragma unroll
      for (int r = 0; r < 4; ++r)
        C[(size_t)(rbase + r) * NA_ + col] = acc[i][j][r] + bb;
    }
  }
}

// ============ out-proj GEMM: C[2048,1024] = A @ Wout^T + bout ============
__global__ __launch_bounds__(256) void gemm_out(
    const float* __restrict__ A, const float* __restrict__ Bm,
    const float* __restrict__ bias, float* __restrict__ C)
{
  __shared__ __align__(16) unsigned char As[2 * 8192];
  __shared__ __align__(16) unsigned char Bs[2 * 8192];
  const int m0 = blockIdx.y * 128, n0 = blockIdx.x * 128;
  GEMM_PROLOGUE_VARS();

  const float* Ap = A + (size_t)(m0 + row) * D_ + half * 16;
  const float* Bp = Bm + (size_t)(n0 + row) * D_ + half * 16;

  f32x4 acc[4][4];
  const f32x4 zf = {0.f, 0.f, 0.f, 0.f};
#pragma unroll
  for (int i = 0; i < 4; ++i)
#pragma unroll
    for (int j = 0; j < 4; ++j) acc[i][j] = zf;

  float4 aA[4], bA[4], aB[4], bB[4];
  GEMM_LOAD(aA, Ap, 0); GEMM_LOAD(bA, Bp, 0);
  GEMM_STORE(As, Bs, aA, bA);
  GEMM_LOAD(aB, Ap, 1); GEMM_LOAD(bB, Bp, 1);
  __syncthreads();

#pragma unroll 1
  for (int s = 0; s < 32; s += 2) {
    GEMM_COMPUTE(As, Bs);
    GEMM_STORE((As + 8192), (Bs + 8192), aB, bB);
    if (s + 2 < 32) { GEMM_LOAD(aA, Ap, s + 2); GEMM_LOAD(bA, Bp, s + 2); }
    __syncthreads();
    GEMM_COMPUTE((As + 8192), (Bs + 8192));
    if (s + 2 < 32) GEMM_STORE(As, Bs, aA, bA);
    if (s + 3 < 32) { GEMM_LOAD(aB, Ap, s + 3); GEMM_LOAD(bB, Bp, s + 3); }
    __syncthreads();
  }

#pragma unroll
  for (int i = 0; i < 4; ++i) {
    const int rbase = m0 + wm + i * 16 + 4 * g;
#pragma unroll
    for (int j = 0; j < 4; ++j) {
      const int col = n0 + wn + j * 16 + lr;
      const float bb = bias[col];
#pragma unroll
      for (int r = 0; r < 4; ++r)
        C[(size_t)(rbase + r) * D_ + col] = acc[i][j][r] + bb;
    }
  }
}

// ============ exterior products + J6 permute from projected columns ============
// One thread per (b,t,h): reads 4x float4 from qkvp cols 3072+, writes Jw, rd, Jwpk.
__global__ __launch_bounds__(256) void exterior_kernel(
    const float* __restrict__ qkvp,
    float* __restrict__ Jw, float* __restrict__ rd,
    unsigned* __restrict__ Jwpk)
{
  const int i = blockIdx.x * 256 + threadIdx.x;   // 32768
  const int h = i & 15;
  const int t = (i >> 4) & 1023;
  const int b = i >> 14;
  const size_t rowt = ((size_t)(b * T_) + t) * NA_;

  float4 p1w = make_float4(0.f, 0.f, 0.f, 0.f);
  if (t > 0) p1w = *(const float4*)(qkvp + rowt - NA_ + 3072 + h * 4);
  const float4 p2w = *(const float4*)(qkvp + rowt + 3136 + h * 4);
  const float4 p1r = *(const float4*)(qkvp + rowt + 3200 + h * 4);
  const float4 p2r = *(const float4*)(qkvp + rowt + 3264 + h * 4);

  const size_t base = ((size_t)(b * H_ + h) * T_ + t) * 6;
  // write line -> Jw (J6 permute/sign) + packed hi/lo
  {
    const float L0 = p1w.x * p2w.y - p1w.y * p2w.x;
    const float L1 = p1w.x * p2w.z - p1w.z * p2w.x;
    const float L2 = p1w.x * p2w.w - p1w.w * p2w.x;
    const float L3 = p1w.y * p2w.z - p1w.z * p2w.y;
    const float L4 = p1w.y * p2w.w - p1w.w * p2w.y;
    const float L5 = p1w.z * p2w.w - p1w.w * p2w.z;
    const float n = sqrtf(L0 * L0 + L1 * L1 + L2 * L2 + L3 * L3 + L4 * L4 + L5 * L5);
    const float inv = 1.f / fmaxf(n, 1e-12f);
    float jv[6] = {L5 * inv, -L4 * inv, L3 * inv, L2 * inv, -L1 * inv, L0 * inv};
#pragma unroll
    for (int k = 0; k < 6; ++k) Jw[base + k] = jv[k];
    unsigned short JH[6], JL[6];
#pragma unroll
    for (int k = 0; k < 6; ++k) hl_split(jv[k], JH[k], JL[k]);
    unsigned* jp = Jwpk + (((size_t)(b * H_ + h) * T_ + t) << 4);
    unsigned h01 = JH[0] | ((unsigned)JH[1] << 16);
    unsigned h23 = JH[2] | ((unsigned)JH[3] << 16);
    unsigned h45 = JH[4] | ((unsigned)JH[5] << 16);
    jp[0] = h01; jp[1] = h23; jp[2] = h45;
    jp[3] = JL[0] | ((unsigned)JL[1] << 16);
    jp[4] = JL[2] | ((unsigned)JL[3] << 16);
    jp[5] = JL[4] | ((unsigned)JL[5] << 16);
    jp[6] = h01; jp[7] = h23; jp[8] = h45;
#pragma unroll
    for (int k = 9; k < 16; ++k) jp[k] = 0;
  }
  // read line -> rd (no permute)
  {
    const float L0 = p1r.x * p2r.y - p1r.y * p2r.x;
    const float L1 = p1r.x * p2r.z - p1r.z * p2r.x;
    const float L2 = p1r.x * p2r.w - p1r.w * p2r.x;
    const float L3 = p1r.y * p2r.z - p1r.z * p2r.y;
    const float L4 = p1r.y * p2r.w - p1r.w * p2r.y;
    const float L5 = p1r.z * p2r.w - p1r.w * p2r.z;
    const float n = sqrtf(L0 * L0 + L1 * L1 + L2 * L2 + L3 * L3 + L4 * L4 + L5 * L5);
    const float inv = 1.f / fmaxf(n, 1e-12f);
    rd[base + 0] = L0 * inv;
    rd[base + 1] = L1 * inv;
    rd[base + 2] = L2 * inv;
    rd[base + 3] = L3 * inv;
    rd[base + 4] = L4 * inv;
    rd[base + 5] = L5 * inv;
  }
}

// ============ causal 6x6 Gram cumsum + rd_M; emits packed hi/lo rdMpk ============
__global__ __launch_bounds__(256) void scan_kernel(
    const float* __restrict__ Jw, const float* __restrict__ rd,
    unsigned* __restrict__ rdMpk)
{
  __shared__ float sc[256][36];
  const int tid = threadIdx.x;
  const int bh = blockIdx.x;
  const float* Jb = Jw + (size_t)bh * T_ * 6;
  const float* Rb = rd + (size_t)bh * T_ * 6;
  const int t0 = tid * 4;

  float M[36];
#pragma unroll
  for (int i = 0; i < 36; ++i) M[i] = 0.f;
  for (int tt = 0; tt < 4; ++tt) {
    float j6[6];
#pragma unroll
    for (int i = 0; i < 6; ++i) j6[i] = Jb[(size_t)(t0 + tt) * 6 + i];
#pragma unroll
    for (int a = 0; a < 6; ++a)
#pragma unroll
      for (int c = 0; c < 6; ++c)
        M[a * 6 + c] = fmaf(j6[a], j6[c], M[a * 6 + c]);
  }
#pragma unroll
  for (int i = 0; i < 36; ++i) sc[tid][i] = M[i];
  __syncthreads();

  float Mp[36];
#pragma unroll
  for (int i = 0; i < 36; ++i) Mp[i] = 0.f;
  for (int j = 0; j < tid; ++j) {
#pragma unroll
    for (int i = 0; i < 36; ++i) Mp[i] += sc[j][i];
  }

  for (int tt = 0; tt < 4; ++tt) {
    const int t = t0 + tt;
    float j6[6], r6[6];
#pragma unroll
    for (int i = 0; i < 6; ++i) { j6[i] = Jb[(size_t)t * 6 + i]; r6[i] = Rb[(size_t)t * 6 + i]; }
#pragma unroll
    for (int a = 0; a < 6; ++a)
#pragma unroll
      for (int c = 0; c < 6; ++c)
        Mp[a * 6 + c] = fmaf(j6[a], j6[c], Mp[a * 6 + c]);
    float s6[6];
#pragma unroll
    for (int jj = 0; jj < 6; ++jj) {
      float s = 0.f;
#pragma unroll
      for (int a = 0; a < 6; ++a) s = fmaf(r6[a], Mp[a * 6 + jj], s);
      s6[jj] = s;
    }
    unsigned short hh[6], ll[6];
#pragma unroll
    for (int i = 0; i < 6; ++i) hl_split(s6[i], hh[i], ll[i]);
    unsigned* ob = rdMpk + (((size_t)bh * T_ + t) << 4);
    unsigned h01 = hh[0] | ((unsigned)hh[1] << 16);
    unsigned h23 = hh[2] | ((unsigned)hh[3] << 16);
    unsigned h45 = hh[4] | ((unsigned)hh[5] << 16);
    ob[0] = h01; ob[1] = h23; ob[2] = h45;
    ob[3] = h01; ob[4] = h23; ob[5] = h45;
    ob[6] = ll[0] | ((unsigned)ll[1] << 16);
    ob[7] = ll[2] | ((unsigned)ll[3] << 16);
    ob[8] = ll[4] | ((unsigned)ll[5] << 16);
#pragma unroll
    for (int i = 9; i < 16; ++i) ob[i] = 0;
  }
}

// ============ MFMA flash attention with eigen bias ============
__global__ __launch_bounds__(256) void attn_mfma(
    const float* __restrict__ qkv,
    const unsigned* __restrict__ Jwpk,
    const unsigned* __restrict__ rdMpk,
    const float* __restrict__ bias_scale,
    float* __restrict__ attnout)
{
  // LDS: KT 64x144B swz bf16 | VT 64x144B transposed | JW 64x16dw | PB 4x16x144B
  __shared__ __align__(16) unsigned char smem[31744];
  unsigned char* KT = smem;
  unsigned char* VT = smem + 9216;
  unsigned*      JW = (unsigned*)(smem + 18432);
  unsigned char* PB = smem + 22528;

  const int gid = blockIdx.x;
  const int bh = gid & 31;
  const int c = (gid < 256) ? (15 - (gid >> 5)) : ((gid - 256) >> 5);  // LPT pairing
  const int b = bh >> 4, h = bh & 15;
  const int tid = threadIdx.x;
  const int w = tid >> 6;
  const int lane = tid & 63;
  const int lr = lane & 15;
  const int g = lane >> 4;
  const int t0 = c * 64;
  const int nT = c + 1;

  const size_t qkvbase = ((size_t)b * T_) * NA_ + h * 64;
  const size_t jb = (size_t)(b * H_ + h) * T_;

  int srow[4], scol[4];
#pragma unroll
  for (int p = 0; p < 4; ++p) {
    const int idx = p * 256 + tid;
    srow[p] = idx >> 4;
    scol[p] = (idx & 15) * 4;
  }

  // ---- stage Q (scaled) into KT, read per-wave A-frags ----
#pragma unroll
  for (int p = 0; p < 4; ++p) {
    const float4 v = *(const float4*)(qkv + qkvbase + (size_t)(t0 + srow[p]) * NA_ + scol[p]);
    const unsigned d0 = bfpack(v.x * 0.125f, v.y * 0.125f);
    const unsigned d1 = bfpack(v.z * 0.125f, v.w * 0.125f);
    const int byte = srow[p] * 144 + ((scol[p] * 2) ^ ((srow[p] & 7) << 4));
    *(uint2*)(KT + byte) = make_uint2(d0, d1);
  }
  __syncthreads();
  bf16x8 qa[2];
  {
    const int qrow = w * 16 + lr;
#pragma unroll
    for (int kb = 0; kb < 2; ++kb) {
      const int byte = qrow * 144 + (((kb * 64) + 16 * g) ^ ((qrow & 7) << 4));
      qa[kb] = *(const bf16x8*)(KT + byte);
    }
  }
  bf16x8 ra;
  {
    const int t = t0 + w * 16 + lr;
    ra = *(const bf16x8*)(rdMpk + ((jb + t) << 4) + g * 4);
  }
  const float bsc = bias_scale[h];
  __syncthreads();

  float m[4], lsum[4];
  f32x4 O[4];
  const f32x4 zf = {0.f, 0.f, 0.f, 0.f};
#pragma unroll
  for (int r = 0; r < 4; ++r) { m[r] = -1e30f; lsum[r] = 0.f; }
#pragma unroll
  for (int d = 0; d < 4; ++d) O[d] = zf;

  // prologue loads
  float4 kreg[4], vreg[4];
  uint4 jreg;
  const int jrow = tid >> 2, jpart = (tid & 3) * 4;
  {
#pragma unroll
    for (int p = 0; p < 4; ++p) {
      const size_t rb = qkvbase + (size_t)srow[p] * NA_ + scol[p];
      kreg[p] = *(const float4*)(qkv + rb + 1024);
      vreg[p] = *(const float4*)(qkv + rb + 2048);
    }
    jreg = *(const uint4*)(Jwpk + ((jb + jrow) << 4) + jpart);
  }

  for (int ti = 0; ti < nT; ++ti) {
    const int s0 = ti * 64;
    __syncthreads();
    // K: row-major swizzled
#pragma unroll
    for (int p = 0; p < 4; ++p) {
      const unsigned d0 = bfpack(kreg[p].x, kreg[p].y);
      const unsigned d1 = bfpack(kreg[p].z, kreg[p].w);
      const int byte = srow[p] * 144 + ((scol[p] * 2) ^ ((srow[p] & 7) << 4));
      *(uint2*)(KT + byte) = make_uint2(d0, d1);
      // V: transposed [d][s]
      const int s = srow[p];
#pragma unroll
      for (int i = 0; i < 4; ++i) {
        const int d = scol[p] + i;
        const float vv = (i == 0) ? vreg[p].x : (i == 1) ? vreg[p].y : (i == 2) ? vreg[p].z : vreg[p].w;
        const int vbyte = d * 144 + ((2 * s) ^ ((d & 7) << 4));
        *(unsigned short*)(VT + vbyte) = f2bf(vv);
      }
    }
    *(uint4*)(JW + jrow * 16 + jpart) = jreg;
    __syncthreads();
    // prefetch next tile
    if (ti + 1 < nT) {
      const int s0n = s0 + 64;
#pragma unroll
      for (int p = 0; p < 4; ++p) {
        const size_t rb = qkvbase + (size_t)(s0n + srow[p]) * NA_ + scol[p];
        kreg[p] = *(const float4*)(qkv + rb + 1024);
        vreg[p] = *(const float4*)(qkv + rb + 2048);
      }
      jreg = *(const uint4*)(Jwpk + ((jb + s0n + jrow) << 4) + jpart);
    }

    // ---- QK^T + bias via MFMA ----
    f32x4 S[4], Sb[4];
#pragma unroll
    for (int cb = 0; cb < 4; ++cb) {
      const int srw = cb * 16 + lr;
      f32x4 a = zf;
#pragma unroll
      for (int kb = 0; kb < 2; ++kb) {
        const int byte = srw * 144 + (((kb * 64) + 16 * g) ^ ((srw & 7) << 4));
        const bf16x8 kf = *(const bf16x8*)(KT + byte);
        a = __builtin_amdgcn_mfma_f32_16x16x32_bf16(qa[kb], kf, a, 0, 0, 0);
      }
      S[cb] = a;
      union { uint4 u; bf16x8 v; } tmp;
      tmp.u = *(const uint4*)(JW + srw * 16 + g * 4);
      Sb[cb] = __builtin_amdgcn_mfma_f32_16x16x32_bf16(ra, tmp.v, zf, 0, 0, 0);
    }

    // ---- online softmax ----
    const bool diag = (s0 == t0);
    float logit[4][4];
#pragma unroll
    for (int cb = 0; cb < 4; ++cb) {
#pragma unroll
      for (int r = 0; r < 4; ++r) {
        float lg = S[cb][r] + fabsf(Sb[cb][r]) * bsc;
        if (diag && (cb * 16 + lr > w * 16 + 4 * g + r)) lg = -1e30f;
        logit[cb][r] = lg;
      }
    }
#pragma unroll
    for (int r = 0; r < 4; ++r) {
      float mx = fmaxf(fmaxf(logit[0][r], logit[1][r]), fmaxf(logit[2][r], logit[3][r]));
      mx = fmaxf(mx, __shfl_xor(mx, 1));
      mx = fmaxf(mx, __shfl_xor(mx, 2));
      mx = fmaxf(mx, __shfl_xor(mx, 4));
      mx = fmaxf(mx, __shfl_xor(mx, 8));
      const float nm = fmaxf(m[r], mx);
      const float sc = __expf(m[r] - nm);
      m[r] = nm;
      lsum[r] *= sc;
#pragma unroll
      for (int d = 0; d < 4; ++d) O[d][r] *= sc;
    }
#pragma unroll
    for (int cb = 0; cb < 4; ++cb) {
#pragma unroll
      for (int r = 0; r < 4; ++r) {
        const float p = __expf(logit[cb][r] - m[r]);
        lsum[r] += p;
        const int q = 4 * g + r;
        const int s = cb * 16 + lr;
        const int byte = w * 2304 + q * 144 + ((2 * s) ^ ((q & 7) << 4));
        *(unsigned short*)(PB + byte) = f2bf(p);
      }
    }
    // same-wave LDS write->read fence
    asm volatile("s_waitcnt lgkmcnt(0)" ::: "memory");
    __builtin_amdgcn_sched_barrier(0);

    // ---- PV via MFMA ----
    bf16x8 pa[2];
#pragma unroll
    for (int kb = 0; kb < 2; ++kb) {
      const int byte = w * 2304 + lr * 144 + (((kb * 64) + 16 * g) ^ ((lr & 7) << 4));
      pa[kb] = *(const bf16x8*)(PB + byte);
    }
#pragma unroll
    for (int db = 0; db < 4; ++db) {
#pragma unroll
      for (int kb = 0; kb < 2; ++kb) {
        const int d = db * 16 + lr;
        const int byte = d * 144 + (((kb * 64) + 16 * g) ^ ((d & 7) << 4));
        const bf16x8 vf = *(const bf16x8*)(VT + byte);
        O[db] = __builtin_amdgcn_mfma_f32_16x16x32_bf16(pa[kb], vf, O[db], 0, 0, 0);
      }
    }
  }

  // ---- finalize ----
#pragma unroll
  for (int r = 0; r < 4; ++r) {
    float l = lsum[r];
    l += __shfl_xor(l, 1);
    l += __shfl_xor(l, 2);
    l += __shfl_xor(l, 4);
    l += __shfl_xor(l, 8);
    lsum[r] = 1.f / l;
  }
  {
    const int qb = w * 16 + 4 * g;
#pragma unroll
    for (int db = 0; db < 4; ++db) {
#pragma unroll
      for (int r = 0; r < 4; ++r) {
        const int t = t0 + qb + r;
        attnout[((size_t)(b * T_ + t)) * 1024 + h * 64 + db * 16 + lr] = O[db][r] * lsum[r];
      }
    }
  }
}

// =============================== launcher ===============================
extern "C" void kernel_launch(void* const* d_in, const int* in_sizes, int n_in,
                              void* d_out, int out_size, void* d_ws, size_t ws_size,
                              hipStream_t stream)
{
  (void)in_sizes; (void)n_in; (void)out_size; (void)ws_size;
  const float* x    = (const float*)d_in[0];
  const float* Wqkv = (const float*)d_in[1];
  const float* bqkv = (const float*)d_in[2];
  const float* W1w  = (const float*)d_in[3];
  const float* W2w  = (const float*)d_in[4];
  const float* W1r  = (const float*)d_in[5];
  const float* W2r  = (const float*)d_in[6];
  const float* bsc  = (const float*)d_in[7];
  const float* Wout = (const float*)d_in[8];
  const float* bout = (const float*)d_in[9];
  float* out = (float*)d_out;

  float*    qkvp    = (float*)d_ws;                       // 2048*3328 f
  float*    Jw      = qkvp + (size_t)B_ * T_ * NA_;       //  196608 f
  float*    rd      = Jw + (size_t)B_ * H_ * T_ * 6;      //  196608 f
  unsigned* Jwpk    = (unsigned*)(rd + (size_t)B_ * H_ * T_ * 6);     // 524288 u32
  unsigned* rdMpk   = Jwpk + ((size_t)B_ * H_ * T_ << 4); // 524288 u32
  float*    attnout = (float*)(rdMpk + ((size_t)B_ * H_ * T_ << 4));  // 2097152 f

  gemm_qkv<<<dim3(NA_ / 128, B_ * T_ / 128), 256, 0, stream>>>(
      x, Wqkv, bqkv, W1w, W2w, W1r, W2r, qkvp);
  exterior_kernel<<<dim3(B_ * T_ * H_ / 256), 256, 0, stream>>>(
      qkvp, Jw, rd, Jwpk);
  scan_kernel<<<dim3(B_ * H_), 256, 0, stream>>>(Jw, rd, rdMpk);
  attn_mfma<<<dim3(B_ * H_ * (T_ / 64)), 256, 0, stream>>>(
      qkvp, Jwpk, rdMpk, bsc, attnout);
  gemm_out<<<dim3(D_ / 128, B_ * T_ / 128), 256, 0, stream>>>(
      attnout, Wout, bout, out);
}